// Round 25
// baseline (89.518 us; speedup 1.0000x reference)
//
#include <hip/hip_runtime.h>

typedef float f32x4 __attribute__((ext_vector_type(4)));

#define D_IN 1024

// tanh(x) = 1 - 2/(exp(2x)+1): v_exp + v_rcp, robust for all x
__device__ __forceinline__ float fast_tanh(float x) {
  float e = __expf(2.0f * x);
  return 1.0f - 2.0f * __builtin_amdgcn_rcpf(e + 1.0f);
}

// ---------------------------------------------------------------------------
// Fused kernel v3: zero cross-wave dependencies.
//  - each wave REDUNDANTLY evolves V (lanes 0..15; ~1.2us, parallel across
//    waves) into its PRIVATE LDS V buffer (no races);
//  - each lane computes its own M-row Mr[16] directly into registers
//    ((i,a) = (g,mz) -- the exact row the tail needs); no Mlds/flag/spin;
//  - phase 1: r19's measured dot body (16 rows/wave, 4 lanes/row) -> dotsL;
//  - phase 2: validated tail, unroll 2 for cross-row shfl ILP, Mr from regs.
// Same-wave LDS write->read ordering (V, dotsL) is the r23/r24-validated
// mechanism. Single __syncthreads (W1 staging), placed AFTER V/M so the W1
// global loads overlap the V/M compute.
// ---------------------------------------------------------------------------
__global__ __launch_bounds__(256, 1) void fused_qenc_kernel(
    const float* __restrict__ x, const float* __restrict__ W1,
    const float* __restrict__ b1, const float* __restrict__ theta,
    const float* __restrict__ Wmu, const float* __restrict__ bmu,
    const float* __restrict__ Wlv, const float* __restrict__ blv,
    float* __restrict__ out, int B) {
  __shared__ f32x4 W1L[1024];          // 16 KB
  __shared__ float VreW[4][16][17];    // per-wave private V (4.25 KB)
  __shared__ float VimW[4][16][17];    // per-wave private V (4.25 KB)
  __shared__ f32x4 dotsL[64];          // 1 KB

  const int tid = threadIdx.x;
  const int lane = tid & 63;
  const int widx = tid >> 6;
  const int wave = blockIdx.x * 4 + widx;
  const int g = lane >> 4;
  const int mz = lane & 15;
  const int p = lane & 3;

  // ---- stage W1 into LDS (issue now; barrier deferred past V/M) ----
  {
    const f32x4* wp = reinterpret_cast<const f32x4*>(W1);
#pragma unroll
    for (int k = 0; k < 4; ++k) W1L[k * 256 + tid] = wp[k * 256 + tid];
  }

  // ---- invariant global loads (overlap everything) ----
  float b1r[4];
#pragma unroll
  for (int j = 0; j < 4; ++j) b1r[j] = b1[j];
  float wmuP[4], wlvP[4];
#pragma unroll
  for (int k = 0; k < 4; ++k) {
    wmuP[k] = Wmu[lane * 4 + (g ^ k)];
    wlvP[k] = Wlv[lane * 4 + (g ^ k)];
  }
  const float bmur = bmu[lane], blvr = blv[lane];
  const size_t lv_base = (size_t)B * 64;

  // ---- per-wave V-evolve (lanes 0..15; validated body) ----
  if (lane < 16) {
    float re[16], im[16];
#pragma unroll
    for (int z = 0; z < 16; ++z) { re[z] = 0.f; im[z] = 0.f; }
    re[lane] = 1.f;
    for (int layer = 0; layer < 2; ++layer) {
#pragma unroll
      for (int q = 0; q < 4; ++q) {
        float th = theta[layer * 4 + q];
        float s, c;
        __sincosf(0.5f * th, &s, &c);
        // Rx
#pragma unroll
        for (int z = 0; z < 16; ++z) {
          if (!((z >> q) & 1)) {
            int z1 = z | (1 << q);
            float ar = re[z], ai = im[z], br = re[z1], bi = im[z1];
            re[z]  = c * ar + s * bi;  im[z]  = c * ai - s * br;
            re[z1] = c * br + s * ai;  im[z1] = c * bi - s * ar;
          }
        }
        // Ry
#pragma unroll
        for (int z = 0; z < 16; ++z) {
          if (!((z >> q) & 1)) {
            int z1 = z | (1 << q);
            float ar = re[z], ai = im[z], br = re[z1], bi = im[z1];
            re[z]  = c * ar - s * br;  im[z]  = c * ai - s * bi;
            re[z1] = s * ar + c * br;  im[z1] = s * ai + c * bi;
          }
        }
        // Rz
#pragma unroll
        for (int z = 0; z < 16; ++z) {
          if (!((z >> q) & 1)) {
            int z1 = z | (1 << q);
            float ar = re[z], ai = im[z], br = re[z1], bi = im[z1];
            re[z]  = c * ar + s * ai;  im[z]  = c * ai - s * ar;
            re[z1] = c * br - s * bi;  im[z1] = c * bi + s * br;
          }
        }
      }
      // CNOT ring (0,1)(1,2)(2,3)(3,0)
      const int cqs[4] = {0, 1, 2, 3};
      const int tqs[4] = {1, 2, 3, 0};
#pragma unroll
      for (int gIdx = 0; gIdx < 4; ++gIdx) {
#pragma unroll
        for (int z = 0; z < 16; ++z) {
          if (((z >> cqs[gIdx]) & 1) && !((z >> tqs[gIdx]) & 1)) {
            int z1 = z | (1 << tqs[gIdx]);
            float tr = re[z], ti = im[z];
            re[z] = re[z1];  im[z] = im[z1];
            re[z1] = tr;     im[z1] = ti;
          }
        }
      }
    }
#pragma unroll
    for (int z = 0; z < 16; ++z) { VreW[widx][z][lane] = re[z]; VimW[widx][z][lane] = im[z]; }
  }

  // ---- per-lane direct M-row into registers (same-wave V read-after-write,
  //      r24-validated mechanism; (i,a)=(g,mz) matches the tail's need) ----
  float Mr[16];
  {
    float ra[16], ia[16];
#pragma unroll
    for (int z = 0; z < 16; ++z) { ra[z] = VreW[widx][z][mz]; ia[z] = VimW[widx][z][mz]; }
#pragma unroll
    for (int b = 0; b < 16; ++b) {
      float acc = 0.f;
#pragma unroll
      for (int z = 0; z < 16; ++z) {
        float sg = ((z >> (3 - g)) & 1) ? -1.f : 1.f;
        acc += sg * (ra[z] * VreW[widx][z][b] + ia[z] * VimW[widx][z][b]);
      }
      Mr[b] = acc;
    }
  }

  __syncthreads();  // W1L ready (cross-wave); V/M compute overlapped its loads

  // ---- phase 1: dots for this wave's 16 rows (r19 validated body) ----
  {
    const int row = wave * 16 + (lane >> 2);
    if (row < B) {
      const float* xr = x + (size_t)row * D_IN;
      float acc[4] = {0.f, 0.f, 0.f, 0.f};
#pragma unroll
      for (int gg = 0; gg < 16; ++gg) {
        const int db = gg * 64 + p * 16;
        f32x4 xv[4];
#pragma unroll
        for (int k = 0; k < 4; ++k)
          xv[k] = *reinterpret_cast<const f32x4*>(xr + db + 4 * k);
#pragma unroll
        for (int k = 0; k < 4; ++k) {
          const int wi = (db >> 2) + k;
          f32x4 xk = xv[k];
#pragma unroll
          for (int j = 0; j < 4; ++j) {
            f32x4 w = W1L[j * 256 + wi];
            acc[j] = fmaf(xk.x, w.x, acc[j]);
            acc[j] = fmaf(xk.y, w.y, acc[j]);
            acc[j] = fmaf(xk.z, w.z, acc[j]);
            acc[j] = fmaf(xk.w, w.w, acc[j]);
          }
        }
      }
#pragma unroll
      for (int j = 0; j < 4; ++j) {
        acc[j] += __shfl_xor(acc[j], 1);
        acc[j] += __shfl_xor(acc[j], 2);
      }
      float outv = (p == 0) ? acc[0] : (p == 1) ? acc[1] : (p == 2) ? acc[2] : acc[3];
      reinterpret_cast<float*>(&dotsL[widx * 16 + (lane >> 2)])[p] = outv;
    }
  }
  // same-wave dotsL write->read (validated); no barrier

  // ---- phase 2: tail, unroll 2 for cross-row shfl ILP ----
#pragma unroll 2
  for (int rr = 0; rr < 16; ++rr) {
    const int r = wave * 16 + rr;
    if (r < B) {
      f32x4 dv = dotsL[widx * 16 + rr];  // uniform address -> LDS broadcast

      float cq[4], sq[4];
      __sincosf(0.5f * fast_tanh(dv.x + b1r[0]), &sq[0], &cq[0]);
      __sincosf(0.5f * fast_tanh(dv.y + b1r[1]), &sq[1], &cq[1]);
      __sincosf(0.5f * fast_tanh(dv.z + b1r[2]), &sq[2], &cq[2]);
      __sincosf(0.5f * fast_tanh(dv.w + b1r[3]), &sq[3], &cq[3]);

      // rank-1 factors of the product state: sv[z] = A[z&3] * Bf[z>>2]
      const float A0 = cq[0] * cq[1], A1 = sq[0] * cq[1];
      const float A2 = cq[0] * sq[1], A3 = sq[0] * sq[1];
      const float B0 = cq[2] * cq[3], B1 = sq[2] * cq[3];
      const float B2 = cq[2] * sq[3], B3 = sq[2] * sq[3];

      // tdot = M_g[mz][:] . sv (Mr in registers)
      float t0 = fmaf(Mr[3], A3, fmaf(Mr[2], A2, fmaf(Mr[1], A1, Mr[0] * A0)));
      float t1 = fmaf(Mr[7], A3, fmaf(Mr[6], A2, fmaf(Mr[5], A1, Mr[4] * A0)));
      float t2 = fmaf(Mr[11], A3, fmaf(Mr[10], A2, fmaf(Mr[9], A1, Mr[8] * A0)));
      float t3 = fmaf(Mr[15], A3, fmaf(Mr[14], A2, fmaf(Mr[13], A1, Mr[12] * A0)));
      float tdot = fmaf(t3, B3, fmaf(t2, B2, fmaf(t1, B1, t0 * B0)));

      // sv[mz] via per-bit selects
      float svm = ((mz & 1) ? sq[0] : cq[0]);
      svm *= ((mz & 2) ? sq[1] : cq[1]);
      svm *= ((mz & 4) ? sq[2] : cq[2]);
      svm *= ((mz & 8) ? sq[3] : cq[3]);

      float pacc = tdot * svm;
#pragma unroll
      for (int off = 8; off; off >>= 1) pacc += __shfl_xor(pacc, off);
      // pacc = qf_g; exchange across 16-lane groups
      float v1 = __shfl_xor(pacc, 16);  // qf_{g^1}
      float v2 = __shfl_xor(pacc, 32);  // qf_{g^2}
      float v3 = __shfl_xor(v1, 32);    // qf_{g^3}

      float mu = fmaf(v3, wmuP[3], fmaf(v2, wmuP[2], fmaf(v1, wmuP[1], fmaf(pacc, wmuP[0], bmur))));
      float lv = fmaf(v3, wlvP[3], fmaf(v2, wlvP[2], fmaf(v1, wlvP[1], fmaf(pacc, wlvP[0], blvr))));
      __builtin_nontemporal_store(mu, out + (size_t)r * 64 + lane);
      __builtin_nontemporal_store(lv, out + lv_base + (size_t)r * 64 + lane);
    }
  }
}

extern "C" void kernel_launch(void* const* d_in, const int* in_sizes, int n_in,
                              void* d_out, int out_size, void* d_ws, size_t ws_size,
                              hipStream_t stream) {
  const float* x   = (const float*)d_in[0];
  const float* W1  = (const float*)d_in[1];
  const float* b1  = (const float*)d_in[2];
  const float* qp  = (const float*)d_in[3];
  const float* Wmu = (const float*)d_in[4];
  const float* bmu = (const float*)d_in[5];
  const float* Wlv = (const float*)d_in[6];
  const float* blv = (const float*)d_in[7];
  float* out = (float*)d_out;

  const int B = out_size / 128;  // out = mu(B,64) ++ logvar(B,64)

  // 64 rows/block (4 waves x 16 rows); B=32768 -> 512 blocks
  int blocks = (B + 63) / 64;
  fused_qenc_kernel<<<blocks, 256, 0, stream>>>(x, W1, b1, qp, Wmu, bmu, Wlv, blv,
                                                out, B);
}

// Round 30
// 33.783 us; speedup vs baseline: 2.6498x; 2.6498x over previous
//
#include <hip/hip_runtime.h>

typedef float f32x4 __attribute__((ext_vector_type(4)));

#define D_IN 1024

// tanh(x) = 1 - 2/(exp(2x)+1): v_exp + v_rcp, robust for all x
__device__ __forceinline__ float fast_tanh(float x) {
  float e = __expf(2.0f * x);
  return 1.0f - 2.0f * __builtin_amdgcn_rcpf(e + 1.0f);
}

// ---------------------------------------------------------------------------
// Fused kernel v2 (round-24 validated, 33.9us, VGPR=60):
//  - wave 0: V-evolve (lanes 0..15) -> M-formation (64 lanes) -> LDS flag ->
//    then its phase 1 (late).
//  - waves 1..3: phase 1 immediately after the W1 barrier; spin on the flag
//    only AFTER phase 1 (M is needed only for phase 2).
// Phase 1 = r19's measured dot body (16 rows/wave, 4 lanes/row, plain loads).
// Phase 2 = validated tail, dv from LDS, Mr read after the flag.
// Register discipline (r25 lesson): M goes through LDS so nothing M-related
// is live across phase 1; Mr loads after phase 1. Do not "optimize" this.
// ---------------------------------------------------------------------------
__global__ __launch_bounds__(256, 1) void fused_qenc_kernel(
    const float* __restrict__ x, const float* __restrict__ W1,
    const float* __restrict__ b1, const float* __restrict__ theta,
    const float* __restrict__ Wmu, const float* __restrict__ bmu,
    const float* __restrict__ Wlv, const float* __restrict__ blv,
    float* __restrict__ out, int B) {
  __shared__ f32x4 W1L[1024];          // 16 KB
  __shared__ float Vre[16][17];
  __shared__ float Vim[16][17];
  __shared__ float Mlds[4][16][16];
  __shared__ f32x4 dotsL[64];          // 1 KB
  __shared__ volatile int mReady;

  const int tid = threadIdx.x;
  if (tid == 0) mReady = 0;

  // ---- stage W1 into LDS (all 256 threads) ----
  {
    const f32x4* wp = reinterpret_cast<const f32x4*>(W1);
#pragma unroll
    for (int k = 0; k < 4; ++k) W1L[k * 256 + tid] = wp[k * 256 + tid];
  }
  __syncthreads();  // W1L ready; mReady=0 visible

  const int lane = tid & 63;
  const int widx = tid >> 6;
  const int wave = blockIdx.x * 4 + widx;
  const int g = lane >> 4;
  const int mz = lane & 15;
  const int p = lane & 3;

  // global invariant loads (issue early; overlap with everything)
  float b1r[4];
#pragma unroll
  for (int j = 0; j < 4; ++j) b1r[j] = b1[j];
  float wmuP[4], wlvP[4];
#pragma unroll
  for (int k = 0; k < 4; ++k) {
    wmuP[k] = Wmu[lane * 4 + (g ^ k)];
    wlvP[k] = Wlv[lane * 4 + (g ^ k)];
  }
  const float bmur = bmu[lane], blvr = blv[lane];
  const size_t lv_base = (size_t)B * 64;

  // ---- wave 0 only: V-evolve + M-formation + flag ----
  if (widx == 0) {
    if (lane < 16) {
      float re[16], im[16];
#pragma unroll
      for (int z = 0; z < 16; ++z) { re[z] = 0.f; im[z] = 0.f; }
      re[lane] = 1.f;
      for (int layer = 0; layer < 2; ++layer) {
#pragma unroll
        for (int q = 0; q < 4; ++q) {
          float th = theta[layer * 4 + q];
          float s, c;
          __sincosf(0.5f * th, &s, &c);
          // Rx
#pragma unroll
          for (int z = 0; z < 16; ++z) {
            if (!((z >> q) & 1)) {
              int z1 = z | (1 << q);
              float ar = re[z], ai = im[z], br = re[z1], bi = im[z1];
              re[z]  = c * ar + s * bi;  im[z]  = c * ai - s * br;
              re[z1] = c * br + s * ai;  im[z1] = c * bi - s * ar;
            }
          }
          // Ry
#pragma unroll
          for (int z = 0; z < 16; ++z) {
            if (!((z >> q) & 1)) {
              int z1 = z | (1 << q);
              float ar = re[z], ai = im[z], br = re[z1], bi = im[z1];
              re[z]  = c * ar - s * br;  im[z]  = c * ai - s * bi;
              re[z1] = s * ar + c * br;  im[z1] = s * ai + c * bi;
            }
          }
          // Rz
#pragma unroll
          for (int z = 0; z < 16; ++z) {
            if (!((z >> q) & 1)) {
              int z1 = z | (1 << q);
              float ar = re[z], ai = im[z], br = re[z1], bi = im[z1];
              re[z]  = c * ar + s * ai;  im[z]  = c * ai - s * ar;
              re[z1] = c * br - s * bi;  im[z1] = c * bi + s * br;
            }
          }
        }
        // CNOT ring (0,1)(1,2)(2,3)(3,0)
        const int cqs[4] = {0, 1, 2, 3};
        const int tqs[4] = {1, 2, 3, 0};
#pragma unroll
        for (int gIdx = 0; gIdx < 4; ++gIdx) {
#pragma unroll
          for (int z = 0; z < 16; ++z) {
            if (((z >> cqs[gIdx]) & 1) && !((z >> tqs[gIdx]) & 1)) {
              int z1 = z | (1 << tqs[gIdx]);
              float tr = re[z], ti = im[z];
              re[z] = re[z1];  im[z] = im[z1];
              re[z1] = tr;     im[z1] = ti;
            }
          }
        }
      }
#pragma unroll
      for (int z = 0; z < 16; ++z) { Vre[z][lane] = re[z]; Vim[z][lane] = im[z]; }
    }
    // same-wave LDS ordering: V writes above complete before reads below
    {
      const int i = lane >> 4, a = lane & 15;
      float ra[16], ia[16];
#pragma unroll
      for (int z = 0; z < 16; ++z) { ra[z] = Vre[z][a]; ia[z] = Vim[z][a]; }
#pragma unroll
      for (int b = 0; b < 16; ++b) {
        float acc = 0.f;
#pragma unroll
        for (int z = 0; z < 16; ++z) {
          float sg = ((z >> (3 - i)) & 1) ? -1.f : 1.f;
          acc += sg * (ra[z] * Vre[z][b] + ia[z] * Vim[z][b]);
        }
        Mlds[i][a][b] = acc;
      }
    }
    __threadfence_block();
    if (lane == 0) mReady = 1;
  }

  // ---- phase 1: dots for this wave's 16 rows (r19 validated body) ----
  {
    const int row = wave * 16 + (lane >> 2);
    if (row < B) {
      const float* xr = x + (size_t)row * D_IN;
      float acc[4] = {0.f, 0.f, 0.f, 0.f};
#pragma unroll
      for (int gg = 0; gg < 16; ++gg) {
        const int db = gg * 64 + p * 16;
        f32x4 xv[4];
#pragma unroll
        for (int k = 0; k < 4; ++k)
          xv[k] = *reinterpret_cast<const f32x4*>(xr + db + 4 * k);
#pragma unroll
        for (int k = 0; k < 4; ++k) {
          const int wi = (db >> 2) + k;
          f32x4 xk = xv[k];
#pragma unroll
          for (int j = 0; j < 4; ++j) {
            f32x4 w = W1L[j * 256 + wi];
            acc[j] = fmaf(xk.x, w.x, acc[j]);
            acc[j] = fmaf(xk.y, w.y, acc[j]);
            acc[j] = fmaf(xk.z, w.z, acc[j]);
            acc[j] = fmaf(xk.w, w.w, acc[j]);
          }
        }
      }
#pragma unroll
      for (int j = 0; j < 4; ++j) {
        acc[j] += __shfl_xor(acc[j], 1);
        acc[j] += __shfl_xor(acc[j], 2);
      }
      float outv = (p == 0) ? acc[0] : (p == 1) ? acc[1] : (p == 2) ? acc[2] : acc[3];
      reinterpret_cast<float*>(&dotsL[widx * 16 + (lane >> 2)])[p] = outv;
    }
  }

  // ---- waves 1..3: wait for M (wave 0 set the flag before its phase 1) ----
  if (widx != 0) {
    while (mReady == 0) __builtin_amdgcn_s_sleep(1);
  }
  __threadfence_block();  // acquire: Mlds writes visible

  float Mr[16];
#pragma unroll
  for (int k = 0; k < 16; ++k) Mr[k] = Mlds[g][mz][k];

  // ---- phase 2: tail for this wave's 16 rows (validated body) ----
#pragma unroll 1
  for (int rr = 0; rr < 16; ++rr) {
    const int r = wave * 16 + rr;
    if (r >= B) break;
    f32x4 dv = dotsL[widx * 16 + rr];  // uniform address -> LDS broadcast

    float cq[4], sq[4];
    __sincosf(0.5f * fast_tanh(dv.x + b1r[0]), &sq[0], &cq[0]);
    __sincosf(0.5f * fast_tanh(dv.y + b1r[1]), &sq[1], &cq[1]);
    __sincosf(0.5f * fast_tanh(dv.z + b1r[2]), &sq[2], &cq[2]);
    __sincosf(0.5f * fast_tanh(dv.w + b1r[3]), &sq[3], &cq[3]);

    // rank-1 factors of the product state: sv[z] = A[z&3] * Bf[z>>2]
    const float A0 = cq[0] * cq[1], A1 = sq[0] * cq[1];
    const float A2 = cq[0] * sq[1], A3 = sq[0] * sq[1];
    const float B0 = cq[2] * cq[3], B1 = sq[2] * cq[3];
    const float B2 = cq[2] * sq[3], B3 = sq[2] * sq[3];

    // tdot = M_g[mz][:] . sv
    float t0 = fmaf(Mr[3], A3, fmaf(Mr[2], A2, fmaf(Mr[1], A1, Mr[0] * A0)));
    float t1 = fmaf(Mr[7], A3, fmaf(Mr[6], A2, fmaf(Mr[5], A1, Mr[4] * A0)));
    float t2 = fmaf(Mr[11], A3, fmaf(Mr[10], A2, fmaf(Mr[9], A1, Mr[8] * A0)));
    float t3 = fmaf(Mr[15], A3, fmaf(Mr[14], A2, fmaf(Mr[13], A1, Mr[12] * A0)));
    float tdot = fmaf(t3, B3, fmaf(t2, B2, fmaf(t1, B1, t0 * B0)));

    // sv[mz] via per-bit selects
    float svm = ((mz & 1) ? sq[0] : cq[0]);
    svm *= ((mz & 2) ? sq[1] : cq[1]);
    svm *= ((mz & 4) ? sq[2] : cq[2]);
    svm *= ((mz & 8) ? sq[3] : cq[3]);

    float pacc = tdot * svm;
#pragma unroll
    for (int off = 8; off; off >>= 1) pacc += __shfl_xor(pacc, off);
    // pacc = qf_g; exchange across 16-lane groups
    float v1 = __shfl_xor(pacc, 16);  // qf_{g^1}
    float v2 = __shfl_xor(pacc, 32);  // qf_{g^2}
    float v3 = __shfl_xor(v1, 32);    // qf_{g^3}

    float mu = fmaf(v3, wmuP[3], fmaf(v2, wmuP[2], fmaf(v1, wmuP[1], fmaf(pacc, wmuP[0], bmur))));
    float lv = fmaf(v3, wlvP[3], fmaf(v2, wlvP[2], fmaf(v1, wlvP[1], fmaf(pacc, wlvP[0], blvr))));
    __builtin_nontemporal_store(mu, out + (size_t)r * 64 + lane);
    __builtin_nontemporal_store(lv, out + lv_base + (size_t)r * 64 + lane);
  }
}

extern "C" void kernel_launch(void* const* d_in, const int* in_sizes, int n_in,
                              void* d_out, int out_size, void* d_ws, size_t ws_size,
                              hipStream_t stream) {
  const float* x   = (const float*)d_in[0];
  const float* W1  = (const float*)d_in[1];
  const float* b1  = (const float*)d_in[2];
  const float* qp  = (const float*)d_in[3];
  const float* Wmu = (const float*)d_in[4];
  const float* bmu = (const float*)d_in[5];
  const float* Wlv = (const float*)d_in[6];
  const float* blv = (const float*)d_in[7];
  float* out = (float*)d_out;

  const int B = out_size / 128;  // out = mu(B,64) ++ logvar(B,64)

  // 64 rows/block (4 waves x 16 rows); B=32768 -> 512 blocks
  int blocks = (B + 63) / 64;
  fused_qenc_kernel<<<blocks, 256, 0, stream>>>(x, W1, b1, qp, Wmu, bmu, Wlv, blv,
                                                out, B);
}